// Round 1
// baseline (8008.708 us; speedup 1.0000x reference)
//
#include <hip/hip_runtime.h>
#include <hip/hip_bf16.h>
#include <math.h>

// Problem constants (B, ST, TT, H, E, V, O) = (64, 1024, 256, 512, 512, 32, 31)
#define B_   64
#define ST_  1024
#define TT_  256
#define H_   512
#define E_   512
#define V_   32
#define O_   31
#define G3_  1536   // 3*H

// ---------------------------------------------------------------------------
// K0a: giV[v, n] = sum_k embed[v,k] * W_ih[n,k] + b_ih[n]   (32 x 1536)
// Input projection depends only on token id (V=32) -> precompute lookup table.
// ---------------------------------------------------------------------------
__global__ __launch_bounds__(256) void k_giv(const float* __restrict__ embed,
                                             const float* __restrict__ W_ih,
                                             const float* __restrict__ b_ih,
                                             float* __restrict__ giV) {
    int idx = blockIdx.x * 256 + threadIdx.x;       // 0 .. 49151
    if (idx >= V_ * G3_) return;
    int v = idx / G3_, n = idx % G3_;
    const float4* e4 = (const float4*)(embed + v * E_);
    const float4* w4 = (const float4*)(W_ih + (size_t)n * E_);
    float acc = 0.f;
#pragma unroll 4
    for (int k = 0; k < E_ / 4; ++k) {
        float4 a = e4[k], b = w4[k];
        acc += a.x * b.x + a.y * b.y + a.z * b.z + a.w * b.w;
    }
    giV[idx] = acc + b_ih[n];
}

// ---------------------------------------------------------------------------
// K0b: transpose fc_W (31 x 1024) -> fc_Wt (1024 x 32), pad col 31 with 0
// ---------------------------------------------------------------------------
__global__ __launch_bounds__(256) void k_fcw_t(const float* __restrict__ fc_W,
                                               float* __restrict__ fc_Wt) {
    int idx = blockIdx.x * 256 + threadIdx.x;       // 0 .. 32767
    int k = idx >> 5, o = idx & 31;
    fc_Wt[idx] = (o < O_) ? fc_W[(size_t)o * 1024 + k] : 0.f;
}

// ---------------------------------------------------------------------------
// K1: one GRU step. Grid = 256 blocks x 256 threads.
// Block (bc, jc) handles b in [bc*16, bc*16+16), j in [jc*8, jc*8+8).
// Each (b, j) pair is computed by 2 threads (K split in halves), combined
// with shfl_xor. Self-contained per block -> no cross-block sync per step.
// ---------------------------------------------------------------------------
__global__ __launch_bounds__(256) void k_gru_step(const float* __restrict__ h_prev,
                                                  int hp_stride,
                                                  const float* __restrict__ giV,
                                                  const int* __restrict__ trg,
                                                  const float* __restrict__ W_hh,
                                                  const float* __restrict__ b_hh,
                                                  float* __restrict__ h_all,
                                                  int t) {
    int tid  = threadIdx.x;
    int jc   = blockIdx.x & 63, bc = blockIdx.x >> 6;
    int pair = tid >> 1, half = tid & 1;
    int bi   = pair >> 3, ji = pair & 7;
    int b    = bc * 16 + bi;
    int j    = jc * 8 + ji;
    int k0   = half * (H_ / 2);

    const float4* h4 = (const float4*)(h_prev + (size_t)b * hp_stride + k0);
    const float4* w0 = (const float4*)(W_hh + (size_t)(j         ) * H_ + k0);
    const float4* w1 = (const float4*)(W_hh + (size_t)(j +   H_  ) * H_ + k0);
    const float4* w2 = (const float4*)(W_hh + (size_t)(j + 2 * H_) * H_ + k0);

    float sr = 0.f, sz = 0.f, sn = 0.f;
#pragma unroll 4
    for (int k = 0; k < H_ / 2 / 4; ++k) {
        float4 hv = h4[k];
        float4 a = w0[k], c = w1[k], d = w2[k];
        sr += hv.x * a.x + hv.y * a.y + hv.z * a.z + hv.w * a.w;
        sz += hv.x * c.x + hv.y * c.y + hv.z * c.z + hv.w * c.w;
        sn += hv.x * d.x + hv.y * d.y + hv.z * d.z + hv.w * d.w;
    }
    sr += __shfl_xor(sr, 1);
    sz += __shfl_xor(sz, 1);
    sn += __shfl_xor(sn, 1);

    if (half == 0) {
        int tok = trg[(size_t)b * TT_ + t];
        const float* gv = giV + (size_t)tok * G3_;
        float gh_r = sr + b_hh[j];
        float gh_z = sz + b_hh[H_ + j];
        float gh_n = sn + b_hh[2 * H_ + j];
        float r = 1.f / (1.f + expf(-(gv[j] + gh_r)));
        float z = 1.f / (1.f + expf(-(gv[H_ + j] + gh_z)));
        float n = tanhf(gv[2 * H_ + j] + r * gh_n);
        float hp = h_prev[(size_t)b * hp_stride + j];
        h_all[(size_t)b * TT_ * H_ + (size_t)t * H_ + j] = (1.f - z) * n + z * hp;
    }
}

// FMA micro-kernel helper for the 4x4 register tiles
#define FMA16(a, bb)                                                     \
    acc[0][0] = fmaf(a.x, bb.x, acc[0][0]);                              \
    acc[0][1] = fmaf(a.x, bb.y, acc[0][1]);                              \
    acc[0][2] = fmaf(a.x, bb.z, acc[0][2]);                              \
    acc[0][3] = fmaf(a.x, bb.w, acc[0][3]);                              \
    acc[1][0] = fmaf(a.y, bb.x, acc[1][0]);                              \
    acc[1][1] = fmaf(a.y, bb.y, acc[1][1]);                              \
    acc[1][2] = fmaf(a.y, bb.z, acc[1][2]);                              \
    acc[1][3] = fmaf(a.y, bb.w, acc[1][3]);                              \
    acc[2][0] = fmaf(a.z, bb.x, acc[2][0]);                              \
    acc[2][1] = fmaf(a.z, bb.y, acc[2][1]);                              \
    acc[2][2] = fmaf(a.z, bb.z, acc[2][2]);                              \
    acc[2][3] = fmaf(a.z, bb.w, acc[2][3]);                              \
    acc[3][0] = fmaf(a.w, bb.x, acc[3][0]);                              \
    acc[3][1] = fmaf(a.w, bb.y, acc[3][1]);                              \
    acc[3][2] = fmaf(a.w, bb.z, acc[3][2]);                              \
    acc[3][3] = fmaf(a.w, bb.w, acc[3][3]);

// ---------------------------------------------------------------------------
// K2: scores[b, t, s] = sum_k h_all[b,t,k] * enc[b,s,k]   (NT GEMM per batch)
// 64x64 tile per block, Kc=16, transposed LDS (float4 LDS reads).
// Grid: (ST/64, TT/64, B)
// ---------------------------------------------------------------------------
__global__ __launch_bounds__(256) void k_scores(const float* __restrict__ h_all,
                                                const float* __restrict__ enc,
                                                float* __restrict__ wgt) {
    __shared__ float As[16][68];
    __shared__ float Bs[16][68];
    int b  = blockIdx.z;
    int m0 = blockIdx.y * 64, n0 = blockIdx.x * 64;
    int tid = threadIdx.x;
    int tx = tid & 15, ty = tid >> 4;
    int lr = tid >> 2, lk = (tid & 3) * 4;

    const float* Abase = h_all + (size_t)b * TT_ * H_ + (size_t)(m0 + lr) * H_ + lk;
    const float* Bbase = enc   + (size_t)b * ST_ * H_ + (size_t)(n0 + lr) * H_ + lk;

    float acc[4][4] = {};
    for (int k0 = 0; k0 < H_; k0 += 16) {
        float4 av = *(const float4*)(Abase + k0);
        float4 bv = *(const float4*)(Bbase + k0);
        __syncthreads();
        As[lk + 0][lr] = av.x; As[lk + 1][lr] = av.y;
        As[lk + 2][lr] = av.z; As[lk + 3][lr] = av.w;
        Bs[lk + 0][lr] = bv.x; Bs[lk + 1][lr] = bv.y;
        Bs[lk + 2][lr] = bv.z; Bs[lk + 3][lr] = bv.w;
        __syncthreads();
#pragma unroll
        for (int kk = 0; kk < 16; ++kk) {
            float4 a  = *(const float4*)&As[kk][ty * 4];
            float4 bb = *(const float4*)&Bs[kk][tx * 4];
            FMA16(a, bb)
        }
    }
#pragma unroll
    for (int i = 0; i < 4; ++i)
#pragma unroll
        for (int jj = 0; jj < 4; ++jj)
            wgt[(size_t)b * TT_ * ST_ + (size_t)(m0 + ty * 4 + i) * ST_ + (n0 + tx * 4 + jj)] = acc[i][jj];
}

// ---------------------------------------------------------------------------
// K3: masked softmax over s (row length 1024). One block per (b, t) row.
// ---------------------------------------------------------------------------
__global__ __launch_bounds__(256) void k_softmax(float* __restrict__ wgt,
                                                 const int* __restrict__ source_len) {
    __shared__ float red[8];
    int row = blockIdx.x;            // b*TT + t
    int b = row >> 8;
    int slen = source_len[b];
    float* W = wgt + (size_t)row * ST_;
    int tid = threadIdx.x;

    float v[4];
    float mx = -3.0e38f;
#pragma unroll
    for (int i = 0; i < 4; ++i) {
        int s = tid + i * 256;
        v[i] = (s < slen) ? W[s] : -1e9f;
        mx = fmaxf(mx, v[i]);
    }
#pragma unroll
    for (int off = 32; off; off >>= 1) mx = fmaxf(mx, __shfl_xor(mx, off));
    int wv = tid >> 6;
    if ((tid & 63) == 0) red[wv] = mx;
    __syncthreads();
    mx = fmaxf(fmaxf(red[0], red[1]), fmaxf(red[2], red[3]));

    float sm = 0.f;
#pragma unroll
    for (int i = 0; i < 4; ++i) {
        v[i] = expf(v[i] - mx);
        sm += v[i];
    }
#pragma unroll
    for (int off = 32; off; off >>= 1) sm += __shfl_xor(sm, off);
    if ((tid & 63) == 0) red[4 + wv] = sm;
    __syncthreads();
    sm = red[4] + red[5] + red[6] + red[7];
    float inv = 1.f / sm;
#pragma unroll
    for (int i = 0; i < 4; ++i)
        W[tid + i * 256] = v[i] * inv;
}

// ---------------------------------------------------------------------------
// K4: ctx[b, t, n] = sum_s wgt[b,t,s] * enc[b,s,n]   (NN GEMM per batch)
// Grid: (H/64, TT/64, B)
// ---------------------------------------------------------------------------
__global__ __launch_bounds__(256) void k_ctx(const float* __restrict__ wgt,
                                             const float* __restrict__ enc,
                                             float* __restrict__ ctx) {
    __shared__ float As[16][68];
    __shared__ float Bs[16][68];
    int b  = blockIdx.z;
    int m0 = blockIdx.y * 64, n0 = blockIdx.x * 64;
    int tid = threadIdx.x;
    int tx = tid & 15, ty = tid >> 4;
    int lr = tid >> 2, lk = (tid & 3) * 4;     // A-tile load mapping
    int bk = tid >> 4, bn = (tid & 15) * 4;    // B-tile load mapping

    const float* Abase = wgt + (size_t)b * TT_ * ST_ + (size_t)(m0 + lr) * ST_ + lk;
    const float* Bbase = enc + (size_t)b * ST_ * H_ + n0 + bn;

    float acc[4][4] = {};
    for (int k0 = 0; k0 < ST_; k0 += 16) {
        float4 av = *(const float4*)(Abase + k0);
        float4 bv = *(const float4*)(Bbase + (size_t)(k0 + bk) * H_);
        __syncthreads();
        As[lk + 0][lr] = av.x; As[lk + 1][lr] = av.y;
        As[lk + 2][lr] = av.z; As[lk + 3][lr] = av.w;
        *(float4*)&Bs[bk][bn] = bv;
        __syncthreads();
#pragma unroll
        for (int kk = 0; kk < 16; ++kk) {
            float4 a  = *(const float4*)&As[kk][ty * 4];
            float4 bb = *(const float4*)&Bs[kk][tx * 4];
            FMA16(a, bb)
        }
    }
#pragma unroll
    for (int i = 0; i < 4; ++i)
#pragma unroll
        for (int jj = 0; jj < 4; ++jj)
            ctx[(size_t)b * TT_ * H_ + (size_t)(m0 + ty * 4 + i) * H_ + (n0 + tx * 4 + jj)] = acc[i][jj];
}

// ---------------------------------------------------------------------------
// K5: out[b,t,o] = (t < trg_len[b]) ? [h|ctx] . fc_W[o] + fc_b[o] : 0
// Block handles 8 rows; 32 lanes per row (o = lane&31, col 31 idle-guarded).
// ---------------------------------------------------------------------------
__global__ __launch_bounds__(256) void k_out(const float* __restrict__ h_all,
                                             const float* __restrict__ ctx,
                                             const float* __restrict__ fc_Wt,
                                             const float* __restrict__ fc_b,
                                             const int* __restrict__ trg_len,
                                             float* __restrict__ out) {
    int tid = threadIdx.x;
    int o = tid & 31;
    int m = blockIdx.x * 8 + (tid >> 5);     // b*TT + t
    int b = m >> 8, t = m & 255;
    const float* xh = h_all + (size_t)m * H_;
    const float* xc = ctx + (size_t)m * H_;
    float acc = (o < O_) ? fc_b[o] : 0.f;
#pragma unroll 4
    for (int k = 0; k < H_; ++k) acc = fmaf(xh[k], fc_Wt[k * 32 + o], acc);
#pragma unroll 4
    for (int k = 0; k < H_; ++k) acc = fmaf(xc[k], fc_Wt[(H_ + k) * 32 + o], acc);
    if (o < O_) {
        float val = (t < trg_len[b]) ? acc : 0.0f;
        out[(size_t)m * O_ + o] = val;
    }
}

// ---------------------------------------------------------------------------
extern "C" void kernel_launch(void* const* d_in, const int* in_sizes, int n_in,
                              void* d_out, int out_size, void* d_ws, size_t ws_size,
                              hipStream_t stream) {
    const int*   trg      = (const int*)d_in[0];
    const int*   trg_len  = (const int*)d_in[1];
    const int*   src_len  = (const int*)d_in[2];
    const float* enc      = (const float*)d_in[3];
    const float* enc_last = (const float*)d_in[4];
    const float* embed    = (const float*)d_in[5];
    const float* W_ih     = (const float*)d_in[6];
    const float* W_hh     = (const float*)d_in[7];
    const float* b_ih     = (const float*)d_in[8];
    const float* b_hh     = (const float*)d_in[9];
    const float* fc_W     = (const float*)d_in[10];
    const float* fc_b     = (const float*)d_in[11];
    float* out = (float*)d_out;

    char* ws = (char*)d_ws;
    float* giV   = (float*)ws;  ws += (size_t)V_ * G3_ * 4;            // 192 KB
    float* fc_Wt = (float*)ws;  ws += (size_t)1024 * 32 * 4;           // 128 KB
    float* h_all = (float*)ws;  ws += (size_t)B_ * TT_ * H_ * 4;       // 32 MB
    float* wgt   = (float*)ws;  ws += (size_t)B_ * TT_ * ST_ * 4;      // 64 MB
    float* ctx   = (float*)ws;  ws += (size_t)B_ * TT_ * H_ * 4;       // 32 MB

    k_giv<<<192, 256, 0, stream>>>(embed, W_ih, b_ih, giV);
    k_fcw_t<<<128, 256, 0, stream>>>(fc_W, fc_Wt);

    for (int t = 0; t < TT_; ++t) {
        const float* hp = t ? (h_all + (size_t)(t - 1) * H_) : enc_last;
        int stride = t ? TT_ * H_ : H_;
        k_gru_step<<<256, 256, 0, stream>>>(hp, stride, giV, trg, W_hh, b_hh, h_all, t);
    }

    k_scores<<<dim3(ST_ / 64, TT_ / 64, B_), 256, 0, stream>>>(h_all, enc, wgt);
    k_softmax<<<B_ * TT_, 256, 0, stream>>>(wgt, src_len);
    k_ctx<<<dim3(H_ / 64, TT_ / 64, B_), 256, 0, stream>>>(wgt, enc, ctx);
    k_out<<<B_ * TT_ / 8, 256, 0, stream>>>(h_all, ctx, fc_Wt, fc_b, trg_len, out);
}

// Round 2
// 3256.121 us; speedup vs baseline: 2.4596x; 2.4596x over previous
//
#include <hip/hip_runtime.h>
#include <hip/hip_bf16.h>
#include <math.h>

// Problem constants (B, ST, TT, H, E, V, O) = (64, 1024, 256, 512, 512, 32, 31)
#define B_   64
#define ST_  1024
#define TT_  256
#define H_   512
#define E_   512
#define V_   32
#define O_   31
#define G3_  1536   // 3*H

// ---------------------------------------------------------------------------
// K0a: giV[v, n] = sum_k embed[v,k] * W_ih[n,k] + b_ih[n]   (32 x 1536)
// ---------------------------------------------------------------------------
__global__ __launch_bounds__(256) void k_giv(const float* __restrict__ embed,
                                             const float* __restrict__ W_ih,
                                             const float* __restrict__ b_ih,
                                             float* __restrict__ giV) {
    int idx = blockIdx.x * 256 + threadIdx.x;       // 0 .. 49151
    if (idx >= V_ * G3_) return;
    int v = idx / G3_, n = idx % G3_;
    const float4* e4 = (const float4*)(embed + v * E_);
    const float4* w4 = (const float4*)(W_ih + (size_t)n * E_);
    float acc = 0.f;
#pragma unroll 4
    for (int k = 0; k < E_ / 4; ++k) {
        float4 a = e4[k], b = w4[k];
        acc += a.x * b.x + a.y * b.y + a.z * b.z + a.w * b.w;
    }
    giV[idx] = acc + b_ih[n];
}

// ---------------------------------------------------------------------------
// K0b: transpose fc_W (31 x 1024) -> fc_Wt (1024 x 32), pad col 31 with 0
// ---------------------------------------------------------------------------
__global__ __launch_bounds__(256) void k_fcw_t(const float* __restrict__ fc_W,
                                               float* __restrict__ fc_Wt) {
    int idx = blockIdx.x * 256 + threadIdx.x;       // 0 .. 32767
    int k = idx >> 5, o = idx & 31;
    fc_Wt[idx] = (o < O_) ? fc_W[(size_t)o * 1024 + k] : 0.f;
}

// ---------------------------------------------------------------------------
// K1 v2: one GRU step. Grid = 512 blocks (bc=8 x jc=64) x 256 threads.
// Block covers b in [bc*8, bc*8+8), h_new j in [jc*8, jc*8+8).
// h_prev (8 rows x 512) staged in LDS. Thread = (b, ks, j): b=tid&7 (so 8
// lanes share each W address -> merged broadcast load), ks=(tid>>3)&3 is a
// 4-way K split (128 each), j=tid>>5. shfl_xor(8|16) reduces the K splits.
// ---------------------------------------------------------------------------
__global__ __launch_bounds__(256) void k_gru_step(const float* __restrict__ h_prev,
                                                  int hp_stride,
                                                  const float* __restrict__ giV,
                                                  const int* __restrict__ trg,
                                                  const float* __restrict__ W_hh,
                                                  const float* __restrict__ b_hh,
                                                  float* __restrict__ h_all,
                                                  int t) {
    __shared__ float hs[8][520];                    // pad 512->520 floats
    int tid = threadIdx.x;
    int jc = blockIdx.x & 63, bc = blockIdx.x >> 6;
    int b0 = bc * 8;

    // stage h_prev: 8 rows x 128 float4 = 1024 float4, 4 per thread
#pragma unroll
    for (int i = 0; i < 4; ++i) {
        int fi = tid + i * 256;                     // 0..1023
        int bl = fi >> 7, k4 = fi & 127;
        float4 v = *(const float4*)(h_prev + (size_t)(b0 + bl) * hp_stride + k4 * 4);
        *(float4*)&hs[bl][k4 * 4] = v;
    }
    __syncthreads();

    int bl = tid & 7;                               // batch within block
    int ks = (tid >> 3) & 3;                        // K-split id
    int jl = tid >> 5;                              // j within block
    int j  = jc * 8 + jl;
    int k0 = ks * 128;

    const float4* w0 = (const float4*)(W_hh + (size_t)(j         ) * H_ + k0);
    const float4* w1 = (const float4*)(W_hh + (size_t)(j +   H_  ) * H_ + k0);
    const float4* w2 = (const float4*)(W_hh + (size_t)(j + 2 * H_) * H_ + k0);
    const float4* h4 = (const float4*)&hs[bl][k0];

    float sr = 0.f, sz = 0.f, sn = 0.f;
#pragma unroll 8
    for (int k = 0; k < 32; ++k) {
        float4 hv = h4[k];
        float4 a = w0[k], c = w1[k], d = w2[k];
        sr += hv.x * a.x + hv.y * a.y + hv.z * a.z + hv.w * a.w;
        sz += hv.x * c.x + hv.y * c.y + hv.z * c.z + hv.w * c.w;
        sn += hv.x * d.x + hv.y * d.y + hv.z * d.z + hv.w * d.w;
    }
    sr += __shfl_xor(sr, 8);  sr += __shfl_xor(sr, 16);
    sz += __shfl_xor(sz, 8);  sz += __shfl_xor(sz, 16);
    sn += __shfl_xor(sn, 8);  sn += __shfl_xor(sn, 16);

    if (ks == 0) {
        int b = b0 + bl;
        int tok = trg[(size_t)b * TT_ + t];
        const float* gv = giV + (size_t)tok * G3_;
        float gh_r = sr + b_hh[j];
        float gh_z = sz + b_hh[H_ + j];
        float gh_n = sn + b_hh[2 * H_ + j];
        float r = 1.f / (1.f + expf(-(gv[j] + gh_r)));
        float z = 1.f / (1.f + expf(-(gv[H_ + j] + gh_z)));
        float n = tanhf(gv[2 * H_ + j] + r * gh_n);
        float hp = hs[bl][j];
        h_all[(size_t)b * TT_ * H_ + (size_t)t * H_ + j] = (1.f - z) * n + z * hp;
    }
}

// FMA micro-kernel helper for the 4x4 register tiles
#define FMA16(a, bb)                                                     \
    acc[0][0] = fmaf(a.x, bb.x, acc[0][0]);                              \
    acc[0][1] = fmaf(a.x, bb.y, acc[0][1]);                              \
    acc[0][2] = fmaf(a.x, bb.z, acc[0][2]);                              \
    acc[0][3] = fmaf(a.x, bb.w, acc[0][3]);                              \
    acc[1][0] = fmaf(a.y, bb.x, acc[1][0]);                              \
    acc[1][1] = fmaf(a.y, bb.y, acc[1][1]);                              \
    acc[1][2] = fmaf(a.y, bb.z, acc[1][2]);                              \
    acc[1][3] = fmaf(a.y, bb.w, acc[1][3]);                              \
    acc[2][0] = fmaf(a.z, bb.x, acc[2][0]);                              \
    acc[2][1] = fmaf(a.z, bb.y, acc[2][1]);                              \
    acc[2][2] = fmaf(a.z, bb.z, acc[2][2]);                              \
    acc[2][3] = fmaf(a.z, bb.w, acc[2][3]);                              \
    acc[3][0] = fmaf(a.w, bb.x, acc[3][0]);                              \
    acc[3][1] = fmaf(a.w, bb.y, acc[3][1]);                              \
    acc[3][2] = fmaf(a.w, bb.z, acc[3][2]);                              \
    acc[3][3] = fmaf(a.w, bb.w, acc[3][3]);

// ---------------------------------------------------------------------------
// K2: scores[b, t, s] = sum_k h_all[b,t,k] * enc[b,s,k]   (NT GEMM per batch)
// ---------------------------------------------------------------------------
__global__ __launch_bounds__(256) void k_scores(const float* __restrict__ h_all,
                                                const float* __restrict__ enc,
                                                float* __restrict__ wgt) {
    __shared__ float As[16][68];
    __shared__ float Bs[16][68];
    int b  = blockIdx.z;
    int m0 = blockIdx.y * 64, n0 = blockIdx.x * 64;
    int tid = threadIdx.x;
    int tx = tid & 15, ty = tid >> 4;
    int lr = tid >> 2, lk = (tid & 3) * 4;

    const float* Abase = h_all + (size_t)b * TT_ * H_ + (size_t)(m0 + lr) * H_ + lk;
    const float* Bbase = enc   + (size_t)b * ST_ * H_ + (size_t)(n0 + lr) * H_ + lk;

    float acc[4][4] = {};
    for (int k0 = 0; k0 < H_; k0 += 16) {
        float4 av = *(const float4*)(Abase + k0);
        float4 bv = *(const float4*)(Bbase + k0);
        __syncthreads();
        As[lk + 0][lr] = av.x; As[lk + 1][lr] = av.y;
        As[lk + 2][lr] = av.z; As[lk + 3][lr] = av.w;
        Bs[lk + 0][lr] = bv.x; Bs[lk + 1][lr] = bv.y;
        Bs[lk + 2][lr] = bv.z; Bs[lk + 3][lr] = bv.w;
        __syncthreads();
#pragma unroll
        for (int kk = 0; kk < 16; ++kk) {
            float4 a  = *(const float4*)&As[kk][ty * 4];
            float4 bb = *(const float4*)&Bs[kk][tx * 4];
            FMA16(a, bb)
        }
    }
#pragma unroll
    for (int i = 0; i < 4; ++i)
#pragma unroll
        for (int jj = 0; jj < 4; ++jj)
            wgt[(size_t)b * TT_ * ST_ + (size_t)(m0 + ty * 4 + i) * ST_ + (n0 + tx * 4 + jj)] = acc[i][jj];
}

// ---------------------------------------------------------------------------
// K3: masked softmax over s (row length 1024). One block per (b, t) row.
// ---------------------------------------------------------------------------
__global__ __launch_bounds__(256) void k_softmax(float* __restrict__ wgt,
                                                 const int* __restrict__ source_len) {
    __shared__ float red[8];
    int row = blockIdx.x;            // b*TT + t
    int b = row >> 8;
    int slen = source_len[b];
    float* W = wgt + (size_t)row * ST_;
    int tid = threadIdx.x;

    float v[4];
    float mx = -3.0e38f;
#pragma unroll
    for (int i = 0; i < 4; ++i) {
        int s = tid + i * 256;
        v[i] = (s < slen) ? W[s] : -1e9f;
        mx = fmaxf(mx, v[i]);
    }
#pragma unroll
    for (int off = 32; off; off >>= 1) mx = fmaxf(mx, __shfl_xor(mx, off));
    int wv = tid >> 6;
    if ((tid & 63) == 0) red[wv] = mx;
    __syncthreads();
    mx = fmaxf(fmaxf(red[0], red[1]), fmaxf(red[2], red[3]));

    float sm = 0.f;
#pragma unroll
    for (int i = 0; i < 4; ++i) {
        v[i] = expf(v[i] - mx);
        sm += v[i];
    }
#pragma unroll
    for (int off = 32; off; off >>= 1) sm += __shfl_xor(sm, off);
    if ((tid & 63) == 0) red[4 + wv] = sm;
    __syncthreads();
    sm = red[4] + red[5] + red[6] + red[7];
    float inv = 1.f / sm;
#pragma unroll
    for (int i = 0; i < 4; ++i)
        W[tid + i * 256] = v[i] * inv;
}

// ---------------------------------------------------------------------------
// K4: ctx[b, t, n] = sum_s wgt[b,t,s] * enc[b,s,n]   (NN GEMM per batch)
// ---------------------------------------------------------------------------
__global__ __launch_bounds__(256) void k_ctx(const float* __restrict__ wgt,
                                             const float* __restrict__ enc,
                                             float* __restrict__ ctx) {
    __shared__ float As[16][68];
    __shared__ float Bs[16][68];
    int b  = blockIdx.z;
    int m0 = blockIdx.y * 64, n0 = blockIdx.x * 64;
    int tid = threadIdx.x;
    int tx = tid & 15, ty = tid >> 4;
    int lr = tid >> 2, lk = (tid & 3) * 4;     // A-tile load mapping
    int bk = tid >> 4, bn = (tid & 15) * 4;    // B-tile load mapping

    const float* Abase = wgt + (size_t)b * TT_ * ST_ + (size_t)(m0 + lr) * ST_ + lk;
    const float* Bbase = enc + (size_t)b * ST_ * H_ + n0 + bn;

    float acc[4][4] = {};
    for (int k0 = 0; k0 < ST_; k0 += 16) {
        float4 av = *(const float4*)(Abase + k0);
        float4 bv = *(const float4*)(Bbase + (size_t)(k0 + bk) * H_);
        __syncthreads();
        As[lk + 0][lr] = av.x; As[lk + 1][lr] = av.y;
        As[lk + 2][lr] = av.z; As[lk + 3][lr] = av.w;
        *(float4*)&Bs[bk][bn] = bv;
        __syncthreads();
#pragma unroll
        for (int kk = 0; kk < 16; ++kk) {
            float4 a  = *(const float4*)&As[kk][ty * 4];
            float4 bb = *(const float4*)&Bs[kk][tx * 4];
            FMA16(a, bb)
        }
    }
#pragma unroll
    for (int i = 0; i < 4; ++i)
#pragma unroll
        for (int jj = 0; jj < 4; ++jj)
            ctx[(size_t)b * TT_ * H_ + (size_t)(m0 + ty * 4 + i) * H_ + (n0 + tx * 4 + jj)] = acc[i][jj];
}

// ---------------------------------------------------------------------------
// K5: out[b,t,o] = (t < trg_len[b]) ? [h|ctx] . fc_W[o] + fc_b[o] : 0
// ---------------------------------------------------------------------------
__global__ __launch_bounds__(256) void k_out(const float* __restrict__ h_all,
                                             const float* __restrict__ ctx,
                                             const float* __restrict__ fc_Wt,
                                             const float* __restrict__ fc_b,
                                             const int* __restrict__ trg_len,
                                             float* __restrict__ out) {
    int tid = threadIdx.x;
    int o = tid & 31;
    int m = blockIdx.x * 8 + (tid >> 5);     // b*TT + t
    int b = m >> 8, t = m & 255;
    const float* xh = h_all + (size_t)m * H_;
    const float* xc = ctx + (size_t)m * H_;
    float acc = (o < O_) ? fc_b[o] : 0.f;
#pragma unroll 4
    for (int k = 0; k < H_; ++k) acc = fmaf(xh[k], fc_Wt[k * 32 + o], acc);
#pragma unroll 4
    for (int k = 0; k < H_; ++k) acc = fmaf(xc[k], fc_Wt[(H_ + k) * 32 + o], acc);
    if (o < O_) {
        float val = (t < trg_len[b]) ? acc : 0.0f;
        out[(size_t)m * O_ + o] = val;
    }
}

// ---------------------------------------------------------------------------
extern "C" void kernel_launch(void* const* d_in, const int* in_sizes, int n_in,
                              void* d_out, int out_size, void* d_ws, size_t ws_size,
                              hipStream_t stream) {
    const int*   trg      = (const int*)d_in[0];
    const int*   trg_len  = (const int*)d_in[1];
    const int*   src_len  = (const int*)d_in[2];
    const float* enc      = (const float*)d_in[3];
    const float* enc_last = (const float*)d_in[4];
    const float* embed    = (const float*)d_in[5];
    const float* W_ih     = (const float*)d_in[6];
    const float* W_hh     = (const float*)d_in[7];
    const float* b_ih     = (const float*)d_in[8];
    const float* b_hh     = (const float*)d_in[9];
    const float* fc_W     = (const float*)d_in[10];
    const float* fc_b     = (const float*)d_in[11];
    float* out = (float*)d_out;

    char* ws = (char*)d_ws;
    float* giV   = (float*)ws;  ws += (size_t)V_ * G3_ * 4;            // 192 KB
    float* fc_Wt = (float*)ws;  ws += (size_t)1024 * 32 * 4;           // 128 KB
    float* h_all = (float*)ws;  ws += (size_t)B_ * TT_ * H_ * 4;       // 32 MB
    float* wgt   = (float*)ws;  ws += (size_t)B_ * TT_ * ST_ * 4;      // 64 MB
    float* ctx   = (float*)ws;  ws += (size_t)B_ * TT_ * H_ * 4;       // 32 MB

    k_giv<<<192, 256, 0, stream>>>(embed, W_ih, b_ih, giV);
    k_fcw_t<<<128, 256, 0, stream>>>(fc_W, fc_Wt);

    for (int t = 0; t < TT_; ++t) {
        const float* hp = t ? (h_all + (size_t)(t - 1) * H_) : enc_last;
        int stride = t ? TT_ * H_ : H_;
        k_gru_step<<<512, 256, 0, stream>>>(hp, stride, giV, trg, W_hh, b_hh, h_all, t);
    }

    k_scores<<<dim3(ST_ / 64, TT_ / 64, B_), 256, 0, stream>>>(h_all, enc, wgt);
    k_softmax<<<B_ * TT_, 256, 0, stream>>>(wgt, src_len);
    k_ctx<<<dim3(H_ / 64, TT_ / 64, B_), 256, 0, stream>>>(wgt, enc, ctx);
    k_out<<<B_ * TT_ / 8, 256, 0, stream>>>(h_all, ctx, fc_Wt, fc_b, trg_len, out);
}